// Round 1
// baseline (2284.542 us; speedup 1.0000x reference)
//
#include <hip/hip_runtime.h>
#include <hip/hip_bf16.h>
#include <math.h>

// Problem constants (ProtoInstanceMultiCrossAttention): C=10, S=10, NQ=30, H=1024
#define C_   10
#define S_   10
#define NQ_  30
#define H_   1024
#define Q_   (C_ * NQ_)     // 300
#define ROWS_ (C_ * (S_ + NQ_))  // 400

// ---------------------------------------------------------------------------
// Kernel 1: f = x @ W1 + b1   (400 x 1024, K=1024)
// 50 blocks x 8 rows, 256 threads; thread owns 4 d-columns (tid + 256j)
// ---------------------------------------------------------------------------
__global__ __launch_bounds__(256) void feat_kernel(
    const float* __restrict__ x, const float* __restrict__ W1,
    const float* __restrict__ b1, float* __restrict__ f) {
  __shared__ float xs[8][H_];
  const int r0 = blockIdx.x * 8;
  const int tid = threadIdx.x;
  for (int t = tid; t < 8 * H_; t += 256) {
    int r = t >> 10, h = t & 1023;
    xs[r][h] = x[(r0 + r) * H_ + h];
  }
  __syncthreads();
  float acc[8][4];
#pragma unroll
  for (int r = 0; r < 8; ++r)
#pragma unroll
    for (int j = 0; j < 4; ++j) acc[r][j] = 0.f;

#pragma unroll 2
  for (int h = 0; h < H_; ++h) {
    float w0 = W1[h * H_ + tid];
    float w1 = W1[h * H_ + tid + 256];
    float w2 = W1[h * H_ + tid + 512];
    float w3 = W1[h * H_ + tid + 768];
#pragma unroll
    for (int r = 0; r < 8; ++r) {
      float xv = xs[r][h];
      acc[r][0] = fmaf(xv, w0, acc[r][0]);
      acc[r][1] = fmaf(xv, w1, acc[r][1]);
      acc[r][2] = fmaf(xv, w2, acc[r][2]);
      acc[r][3] = fmaf(xv, w3, acc[r][3]);
    }
  }
#pragma unroll
  for (int r = 0; r < 8; ++r)
#pragma unroll
    for (int j = 0; j < 4; ++j) {
      int d = tid + 256 * j;
      f[(r0 + r) * H_ + d] = acc[r][j] + b1[d];
    }
}

// ---------------------------------------------------------------------------
// Kernel 2: a_s = sf @ Ws (100 rows), a_q = qf @ Wq (300 rows)
// Blocks [0,13): support, [13,51): query. Output layout: a[0..100)=a_s (c*10+s),
// a[100..400)=a_q (query index q).
// ---------------------------------------------------------------------------
__global__ __launch_bounds__(256) void proj_kernel(
    const float* __restrict__ f, const float* __restrict__ W2,
    float* __restrict__ a) {
  const int b = blockIdx.x;
  const bool isSup = (b < 13);
  const int i0 = isSup ? b * 8 : (b - 13) * 8;
  const int n = isSup ? 100 : 300;
  const float* __restrict__ W = isSup ? W2 : (W2 + H_ * H_);

  __shared__ float fs[8][H_];
  const int tid = threadIdx.x;
  for (int t = tid; t < 8 * H_; t += 256) {
    int r = t >> 10, h = t & 1023;
    int i = i0 + r;
    if (i >= n) i = n - 1;  // clamp (stores guarded below)
    int row = isSup ? ((i / 10) * 40 + (i % 10)) : ((i / 30) * 40 + 10 + (i % 30));
    fs[r][h] = f[row * H_ + h];
  }
  __syncthreads();
  float acc[8][4];
#pragma unroll
  for (int r = 0; r < 8; ++r)
#pragma unroll
    for (int j = 0; j < 4; ++j) acc[r][j] = 0.f;

#pragma unroll 2
  for (int h = 0; h < H_; ++h) {
    float w0 = W[h * H_ + tid];
    float w1 = W[h * H_ + tid + 256];
    float w2 = W[h * H_ + tid + 512];
    float w3 = W[h * H_ + tid + 768];
#pragma unroll
    for (int r = 0; r < 8; ++r) {
      float xv = fs[r][h];
      acc[r][0] = fmaf(xv, w0, acc[r][0]);
      acc[r][1] = fmaf(xv, w1, acc[r][1]);
      acc[r][2] = fmaf(xv, w2, acc[r][2]);
      acc[r][3] = fmaf(xv, w3, acc[r][3]);
    }
  }
#pragma unroll
  for (int r = 0; r < 8; ++r) {
    int i = i0 + r;
    if (i < n) {
      int o = isSup ? i : (100 + i);
#pragma unroll
      for (int j = 0; j < 4; ++j) {
        int d = tid + 256 * j;
        a[o * H_ + d] = acc[r][j];
      }
    }
  }
}

// ---------------------------------------------------------------------------
// Kernel 3 (dominant): logits[q,c,s] = sum_d tanh(a_s[c,s,d] + a_q[q,d] + b2[d]
//                     + sum_h |sf[c,s,h]-qf[q,h]|*Wc[h,d] + sf*qf*Wd[h,d])
// Grid: 10 c x 150 q-tiles (2 queries each) = 1500 blocks, 256 threads.
// Thread owns 4 d-columns; acc[2 q][10 s][4 d].
// ---------------------------------------------------------------------------
__global__ __launch_bounds__(256) void mca_kernel(
    const float* __restrict__ f, const float* __restrict__ a,
    const float* __restrict__ W2, const float* __restrict__ b2,
    float* __restrict__ logits) {
  __shared__ float sfl[S_][H_];   // 40 KB
  __shared__ float qfl[2][H_];    // 8 KB
  __shared__ float red[4][20];

  const int c = blockIdx.x / 150;
  const int qt = blockIdx.x % 150;
  const int q0 = qt * 2;
  const int tid = threadIdx.x;

  for (int t = tid; t < S_ * H_; t += 256) {
    int s = t >> 10, h = t & 1023;
    sfl[s][h] = f[(c * 40 + s) * H_ + h];
  }
  for (int t = tid; t < 2 * H_; t += 256) {
    int j = t >> 10, h = t & 1023;
    int q = q0 + j;
    int row = (q / 30) * 40 + 10 + (q % 30);
    qfl[j][h] = f[row * H_ + h];
  }
  __syncthreads();

  const float* __restrict__ Wc = W2 + 2 * H_ * H_;
  const float* __restrict__ Wd = W2 + 3 * H_ * H_;

  float acc[2][S_][4];
#pragma unroll
  for (int qq = 0; qq < 2; ++qq)
#pragma unroll
    for (int s = 0; s < S_; ++s)
#pragma unroll
      for (int j = 0; j < 4; ++j) acc[qq][s][j] = 0.f;

#pragma unroll 2
  for (int h = 0; h < H_; ++h) {
    float wc[4], wd[4];
#pragma unroll
    for (int j = 0; j < 4; ++j) {
      wc[j] = Wc[h * H_ + tid + 256 * j];
      wd[j] = Wd[h * H_ + tid + 256 * j];
    }
    float sv[S_];
#pragma unroll
    for (int s = 0; s < S_; ++s) sv[s] = sfl[s][h];
#pragma unroll
    for (int qq = 0; qq < 2; ++qq) {
      float qv = qfl[qq][h];
#pragma unroll
      for (int s = 0; s < S_; ++s) {
        float d1 = fabsf(sv[s] - qv);
        float d2 = sv[s] * qv;
#pragma unroll
        for (int j = 0; j < 4; ++j)
          acc[qq][s][j] = fmaf(d1, wc[j], fmaf(d2, wd[j], acc[qq][s][j]));
      }
    }
  }

  // Epilogue: add a_s + a_q + b2, tanh, reduce over d.
  const int lane = tid & 63;
  const int wave = tid >> 6;
#pragma unroll
  for (int qq = 0; qq < 2; ++qq) {
    const int q = q0 + qq;
#pragma unroll
    for (int s = 0; s < S_; ++s) {
      float part = 0.f;
#pragma unroll
      for (int j = 0; j < 4; ++j) {
        int d = tid + 256 * j;
        float v = acc[qq][s][j] + a[(c * 10 + s) * H_ + d] + a[(100 + q) * H_ + d] + b2[d];
        part += tanhf(v);
      }
      for (int off = 32; off; off >>= 1) part += __shfl_down(part, off);
      if (lane == 0) red[wave][qq * 10 + s] = part;
    }
  }
  __syncthreads();
  if (tid < 20) {
    float v = red[0][tid] + red[1][tid] + red[2][tid] + red[3][tid];
    int qq = tid / 10, s = tid % 10;
    logits[((q0 + qq) * 10 + c) * 10 + s] = v;
  }
}

// ---------------------------------------------------------------------------
// Kernel 4: softmax over s, proto = score @ support, dists = ||proto - query||^2
// 300 blocks (one per q), 256 threads.
// ---------------------------------------------------------------------------
__global__ __launch_bounds__(256) void out_kernel(
    const float* __restrict__ x, const float* __restrict__ logits,
    float* __restrict__ dists) {
  const int q = blockIdx.x;
  const int tid = threadIdx.x;
  const int lane = tid & 63;
  const int wave = tid >> 6;
  __shared__ float qrow[H_];
  __shared__ float red[4];

  const int qr = (q / 30) * 40 + 10 + (q % 30);
  for (int i = tid; i < H_; i += 256) qrow[i] = x[qr * H_ + i];
  __syncthreads();

  for (int c = 0; c < C_; ++c) {
    // softmax over s (all threads redundantly; 10 elements)
    float l[S_];
    float m = -1e30f;
#pragma unroll
    for (int s = 0; s < S_; ++s) {
      l[s] = logits[(q * 10 + c) * 10 + s];
      m = fmaxf(m, l[s]);
    }
    float sum = 0.f;
    float sc[S_];
#pragma unroll
    for (int s = 0; s < S_; ++s) {
      sc[s] = __expf(l[s] - m);
      sum += sc[s];
    }
    float inv = 1.f / sum;
#pragma unroll
    for (int s = 0; s < S_; ++s) sc[s] *= inv;

    float part = 0.f;
    for (int i = tid; i < H_; i += 256) {
      float p = 0.f;
#pragma unroll
      for (int s = 0; s < S_; ++s) p = fmaf(sc[s], x[(c * 40 + s) * H_ + i], p);
      float d = p - qrow[i];
      part = fmaf(d, d, part);
    }
    for (int off = 32; off; off >>= 1) part += __shfl_down(part, off);
    if (lane == 0) red[wave] = part;
    __syncthreads();
    if (tid == 0) dists[q * 10 + c] = red[0] + red[1] + red[2] + red[3];
    __syncthreads();
  }
}

// ---------------------------------------------------------------------------
extern "C" void kernel_launch(void* const* d_in, const int* in_sizes, int n_in,
                              void* d_out, int out_size, void* d_ws, size_t ws_size,
                              hipStream_t stream) {
  const float* x  = (const float*)d_in[0];
  const float* W1 = (const float*)d_in[1];
  const float* b1 = (const float*)d_in[2];
  const float* W2 = (const float*)d_in[3];
  const float* b2 = (const float*)d_in[4];
  float* out = (float*)d_out;

  float* f = (float*)d_ws;                 // 400*1024
  float* a = f + ROWS_ * H_;               // 400*1024 (100 sup + 300 query)
  float* logits = a + ROWS_ * H_;          // 300*10*10

  feat_kernel<<<ROWS_ / 8, 256, 0, stream>>>(x, W1, b1, f);
  proj_kernel<<<13 + 38, 256, 0, stream>>>(f, W2, a);
  mca_kernel<<<C_ * (Q_ / 2), 256, 0, stream>>>(f, a, W2, b2, logits);
  out_kernel<<<Q_, 256, 0, stream>>>(x, logits, out);
}

// Round 2
// 654.778 us; speedup vs baseline: 3.4890x; 3.4890x over previous
//
#include <hip/hip_runtime.h>
#include <hip/hip_bf16.h>
#include <math.h>

// ProtoInstanceMultiCrossAttention: C=10, S=10, NQ=30, H=1024
#define C_   10
#define S_   10
#define NQ_  30
#define H_   1024
#define Q_   300
#define ROWS_ 400

typedef __attribute__((ext_vector_type(8))) short s16x8;   // 8 bf16 (4 VGPRs)
typedef __attribute__((ext_vector_type(4))) float f32x4;   // MFMA acc

static __device__ __forceinline__ short f2b(float f) {
  __hip_bfloat16 h = __float2bfloat16(f);
  return __builtin_bit_cast(short, h);
}

// ---------------------------------------------------------------------------
// Kernel 1: f = x @ W1 + b1   (400 x 1024, K=1024)  -- fp32 VALU (small)
// ---------------------------------------------------------------------------
__global__ __launch_bounds__(256) void feat_kernel(
    const float* __restrict__ x, const float* __restrict__ W1,
    const float* __restrict__ b1, float* __restrict__ f) {
  __shared__ float xs[8][H_];
  const int r0 = blockIdx.x * 8;
  const int tid = threadIdx.x;
  for (int t = tid; t < 8 * H_; t += 256) {
    int r = t >> 10, h = t & 1023;
    xs[r][h] = x[(r0 + r) * H_ + h];
  }
  __syncthreads();
  float acc[8][4];
#pragma unroll
  for (int r = 0; r < 8; ++r)
#pragma unroll
    for (int j = 0; j < 4; ++j) acc[r][j] = 0.f;
#pragma unroll 2
  for (int h = 0; h < H_; ++h) {
    float w0 = W1[h * H_ + tid];
    float w1 = W1[h * H_ + tid + 256];
    float w2 = W1[h * H_ + tid + 512];
    float w3 = W1[h * H_ + tid + 768];
#pragma unroll
    for (int r = 0; r < 8; ++r) {
      float xv = xs[r][h];
      acc[r][0] = fmaf(xv, w0, acc[r][0]);
      acc[r][1] = fmaf(xv, w1, acc[r][1]);
      acc[r][2] = fmaf(xv, w2, acc[r][2]);
      acc[r][3] = fmaf(xv, w3, acc[r][3]);
    }
  }
#pragma unroll
  for (int r = 0; r < 8; ++r)
#pragma unroll
    for (int j = 0; j < 4; ++j) {
      int d = tid + 256 * j;
      f[(r0 + r) * H_ + d] = acc[r][j] + b1[d];
    }
}

// ---------------------------------------------------------------------------
// Kernel 2: a_s = sf @ Ws (100 rows), a_q = qf @ Wq + b2 (300 rows)
// ---------------------------------------------------------------------------
__global__ __launch_bounds__(256) void proj_kernel(
    const float* __restrict__ f, const float* __restrict__ W2,
    const float* __restrict__ b2, float* __restrict__ a) {
  const int b = blockIdx.x;
  const bool isSup = (b < 13);
  const int i0 = isSup ? b * 8 : (b - 13) * 8;
  const int n = isSup ? 100 : 300;
  const float* __restrict__ W = isSup ? W2 : (W2 + H_ * H_);

  __shared__ float fs[8][H_];
  const int tid = threadIdx.x;
  for (int t = tid; t < 8 * H_; t += 256) {
    int r = t >> 10, h = t & 1023;
    int i = i0 + r;
    if (i >= n) i = n - 1;
    int row = isSup ? ((i / 10) * 40 + (i % 10)) : ((i / 30) * 40 + 10 + (i % 30));
    fs[r][h] = f[row * H_ + h];
  }
  __syncthreads();
  float acc[8][4];
#pragma unroll
  for (int r = 0; r < 8; ++r)
#pragma unroll
    for (int j = 0; j < 4; ++j) acc[r][j] = 0.f;
#pragma unroll 2
  for (int h = 0; h < H_; ++h) {
    float w0 = W[h * H_ + tid];
    float w1 = W[h * H_ + tid + 256];
    float w2 = W[h * H_ + tid + 512];
    float w3 = W[h * H_ + tid + 768];
#pragma unroll
    for (int r = 0; r < 8; ++r) {
      float xv = fs[r][h];
      acc[r][0] = fmaf(xv, w0, acc[r][0]);
      acc[r][1] = fmaf(xv, w1, acc[r][1]);
      acc[r][2] = fmaf(xv, w2, acc[r][2]);
      acc[r][3] = fmaf(xv, w3, acc[r][3]);
    }
  }
#pragma unroll
  for (int r = 0; r < 8; ++r) {
    int i = i0 + r;
    if (i < n) {
      int o = isSup ? i : (100 + i);
#pragma unroll
      for (int j = 0; j < 4; ++j) {
        int d = tid + 256 * j;
        a[o * H_ + d] = acc[r][j] + (isSup ? 0.f : b2[d]);
      }
    }
  }
}

// ---------------------------------------------------------------------------
// Kernel 3: Bt[n][k] = bf16(W[k][n]) for Wc, Wd  (1024x1024 each)
// ---------------------------------------------------------------------------
__global__ __launch_bounds__(256) void trans_kernel(
    const float* __restrict__ W2, unsigned short* __restrict__ Btc,
    unsigned short* __restrict__ Btd) {
  const int b = blockIdx.x;
  const int mat = b >> 8;            // 0=Wc, 1=Wd
  const int kt = (b >> 4) & 15;
  const int ntl = b & 15;
  const float* __restrict__ src = W2 + (size_t)(2 + mat) * H_ * H_;
  unsigned short* __restrict__ dst = mat ? Btd : Btc;
  __shared__ float tl[64][65];
  const int tid = threadIdx.x;
#pragma unroll
  for (int i = 0; i < 16; ++i) {
    int idx = tid + i * 256;
    int r = idx >> 6, cl = idx & 63;
    tl[r][cl] = src[(kt * 64 + r) * H_ + ntl * 64 + cl];
  }
  __syncthreads();
#pragma unroll
  for (int i = 0; i < 16; ++i) {
    int idx = tid + i * 256;
    int nr = idx >> 6, kc = idx & 63;
    dst[(size_t)(ntl * 64 + nr) * H_ + kt * 64 + kc] = (unsigned short)f2b(tl[kc][nr]);
  }
}

// ---------------------------------------------------------------------------
// Kernel 4 (dominant): bf16 MFMA fused mca.
//   A[row][dualk] : row = 10*qloc + s (BM=160 = 16q x 10s),
//                   dualk<32 -> |sf-qf|, dualk>=32 -> sf*qf  (src k slice of 32)
//   B = Bt tile [256 n][64 dualk], LDS XOR-swizzled (T2).
//   K-loop: 32 steps of 32 source-k. Epilogue: +a_s+a_q(+b2), tanh, col-sum,
//   shfl-reduce over 16 col-lanes, atomicAdd into logits.
// Grid: c(10) x qt(19) x nt(4) = 760 blocks, 512 threads (8 waves).
// ---------------------------------------------------------------------------
__global__ __launch_bounds__(512) void mca_mfma_kernel(
    const float* __restrict__ f, const float* __restrict__ a,
    const unsigned short* __restrict__ Btc, const unsigned short* __restrict__ Btd,
    float* __restrict__ logits) {
  const int b = blockIdx.x;
  const int nt = b & 3;
  const int qt = (b >> 2) % 19;
  const int c = (b >> 2) / 19;
  const int q0 = qt * 16;
  const int n0 = nt * 256;

  __shared__ unsigned short Als[160 * 64];  // 20 KB, rows 128B, XOR-swizzled
  __shared__ unsigned short Bls[256 * 64];  // 32 KB, rows 128B, XOR-swizzled
  __shared__ float sfl[10][36];
  __shared__ float qfl[16][36];

  const int tid = threadIdx.x;
  const int w = tid >> 6;
  const int lane = tid & 63;

  f32x4 acc[10][2];
#pragma unroll
  for (int m = 0; m < 10; ++m)
#pragma unroll
    for (int nf = 0; nf < 2; ++nf) acc[m][nf] = (f32x4)(0.f);

  // B-staging thread mapping (fixed across K-steps)
  const int bn = tid >> 1;        // 0..255  (tile n-row)
  const int bm = tid & 1;         // 0=Btc half, 1=Btd half
  const unsigned short* __restrict__ bmat = bm ? Btd : Btc;

  // A-gen helper values
  const int frow = lane & 15;
  const int fkb = (lane >> 4) * 16;  // byte offset of k-group within row

  for (int ks = 0; ks < 32; ++ks) {
    const int kg = ks * 32;

    // ---- issue B global loads (to regs) early
    const s16x8* __restrict__ bsrc =
        (const s16x8*)(bmat + (size_t)(n0 + bn) * H_ + kg);
    s16x8 br0 = bsrc[0], br1 = bsrc[1], br2 = bsrc[2], br3 = bsrc[3];

    // ---- stage sf/qf fp32 slices (26 rows x 32 f32)
    if (tid < 208) {
      int r = tid >> 3, seg = tid & 7;
      if (r < 10) {
        *(float4*)&sfl[r][seg * 4] =
            *(const float4*)&f[(c * 40 + r) * H_ + kg + seg * 4];
      } else {
        int q = q0 + (r - 10);
        if (q > 299) q = 299;
        int grow = (q / 30) * 40 + 10 + (q % 30);
        *(float4*)&qfl[r - 10][seg * 4] =
            *(const float4*)&f[grow * H_ + kg + seg * 4];
      }
    }
    __syncthreads();  // sfq visible; prev MFMA reads done before A/B overwrite

    // ---- write B tile (swizzled)
    {
      unsigned base = (unsigned)(bn * 128 + bm * 64);
      unsigned sw = (unsigned)((bn & 7) << 4);
      *(s16x8*)((char*)Bls + ((base + 0) ^ sw)) = br0;
      *(s16x8*)((char*)Bls + ((base + 16) ^ sw)) = br1;
      *(s16x8*)((char*)Bls + ((base + 32) ^ sw)) = br2;
      *(s16x8*)((char*)Bls + ((base + 48) ^ sw)) = br3;
    }

    // ---- generate A tile: 640 tasks (row, 8-k quarter)
#define GEN_TASK(TAU)                                                          \
  {                                                                            \
    int row = (TAU) >> 2, qtr = (TAU)&3;                                       \
    int qloc = row / 10, s = row - qloc * 10;                                  \
    float4 sa = *(const float4*)&sfl[s][qtr * 8];                              \
    float4 sb = *(const float4*)&sfl[s][qtr * 8 + 4];                          \
    float4 qa = *(const float4*)&qfl[qloc][qtr * 8];                           \
    float4 qb = *(const float4*)&qfl[qloc][qtr * 8 + 4];                       \
    s16x8 d1, d2;                                                              \
    d1[0] = f2b(fabsf(sa.x - qa.x)); d2[0] = f2b(sa.x * qa.x);                 \
    d1[1] = f2b(fabsf(sa.y - qa.y)); d2[1] = f2b(sa.y * qa.y);                 \
    d1[2] = f2b(fabsf(sa.z - qa.z)); d2[2] = f2b(sa.z * qa.z);                 \
    d1[3] = f2b(fabsf(sa.w - qa.w)); d2[3] = f2b(sa.w * qa.w);                 \
    d1[4] = f2b(fabsf(sb.x - qb.x)); d2[4] = f2b(sb.x * qb.x);                 \
    d1[5] = f2b(fabsf(sb.y - qb.y)); d2[5] = f2b(sb.y * qb.y);                 \
    d1[6] = f2b(fabsf(sb.z - qb.z)); d2[6] = f2b(sb.z * qb.z);                 \
    d1[7] = f2b(fabsf(sb.w - qb.w)); d2[7] = f2b(sb.w * qb.w);                 \
    unsigned sw = (unsigned)((row & 7) << 4);                                  \
    unsigned base = (unsigned)(row * 128 + qtr * 16);                          \
    *(s16x8*)((char*)Als + (base ^ sw)) = d1;                                  \
    *(s16x8*)((char*)Als + ((base + 64) ^ sw)) = d2;                           \
  }
    GEN_TASK(tid);
    if (tid < 128) GEN_TASK(512 + tid);
#undef GEN_TASK

    __syncthreads();

    // ---- MFMA: dual-k 64 = 2 kk-steps of 32
    const unsigned swf = (unsigned)((frow & 7) << 4);
#pragma unroll
    for (int kk = 0; kk < 2; ++kk) {
      const unsigned kbyte = (unsigned)(fkb + kk * 64);
      const int brow0 = w * 32 + frow;
      s16x8 bf0 = *(const s16x8*)((char*)Bls + (((unsigned)(brow0 * 128) + kbyte) ^ swf));
      s16x8 bf1 = *(const s16x8*)((char*)Bls + (((unsigned)((brow0 + 16) * 128) + kbyte) ^ swf));
#pragma unroll
      for (int m = 0; m < 10; ++m) {
        int ar = m * 16 + frow;
        s16x8 af = *(const s16x8*)((char*)Als + (((unsigned)(ar * 128) + kbyte) ^ swf));
        acc[m][0] = __builtin_amdgcn_mfma_f32_16x16x32_bf16(af, bf0, acc[m][0], 0, 0, 0);
        acc[m][1] = __builtin_amdgcn_mfma_f32_16x16x32_bf16(af, bf1, acc[m][1], 0, 0, 0);
      }
    }
    __syncthreads();
  }

  // ---- epilogue: +a_s +a_q(+b2 folded), tanh, sum over d, reduce, atomicAdd
  const int col = n0 + w * 32 + (lane & 15);
  const int rgrp = (lane >> 4) * 4;
#pragma unroll
  for (int m = 0; m < 10; ++m) {
#pragma unroll
    for (int r = 0; r < 4; ++r) {
      int row = 16 * m + rgrp + r;
      int qloc = row / 10, s = row - qloc * 10;
      int q = q0 + qloc;
      float v0 = acc[m][0][r] + a[(size_t)(c * 10 + s) * H_ + col] +
                 a[(size_t)(100 + q) * H_ + col];
      float v1 = acc[m][1][r] + a[(size_t)(c * 10 + s) * H_ + col + 16] +
                 a[(size_t)(100 + q) * H_ + col + 16];
      float t = tanhf(v0) + tanhf(v1);
      t += __shfl_xor(t, 1);
      t += __shfl_xor(t, 2);
      t += __shfl_xor(t, 4);
      t += __shfl_xor(t, 8);
      if ((lane & 15) == 0 && q < 300)
        atomicAdd(&logits[(q * 10 + c) * 10 + s], t);
    }
  }
}

// ---------------------------------------------------------------------------
// Kernel 5: softmax over s, proto, dists (unchanged, passed round 1)
// ---------------------------------------------------------------------------
__global__ __launch_bounds__(256) void out_kernel(
    const float* __restrict__ x, const float* __restrict__ logits,
    float* __restrict__ dists) {
  const int q = blockIdx.x;
  const int tid = threadIdx.x;
  const int lane = tid & 63;
  const int wave = tid >> 6;
  __shared__ float qrow[H_];
  __shared__ float red[4];

  const int qr = (q / 30) * 40 + 10 + (q % 30);
  for (int i = tid; i < H_; i += 256) qrow[i] = x[qr * H_ + i];
  __syncthreads();

  for (int c = 0; c < C_; ++c) {
    float l[S_];
    float m = -1e30f;
#pragma unroll
    for (int s = 0; s < S_; ++s) {
      l[s] = logits[(q * 10 + c) * 10 + s];
      m = fmaxf(m, l[s]);
    }
    float sum = 0.f;
    float sc[S_];
#pragma unroll
    for (int s = 0; s < S_; ++s) {
      sc[s] = __expf(l[s] - m);
      sum += sc[s];
    }
    float inv = 1.f / sum;
#pragma unroll
    for (int s = 0; s < S_; ++s) sc[s] *= inv;

    float part = 0.f;
    for (int i = tid; i < H_; i += 256) {
      float p = 0.f;
#pragma unroll
      for (int s = 0; s < S_; ++s) p = fmaf(sc[s], x[(c * 40 + s) * H_ + i], p);
      float d = p - qrow[i];
      part = fmaf(d, d, part);
    }
    for (int off = 32; off; off >>= 1) part += __shfl_down(part, off);
    if (lane == 0) red[wave] = part;
    __syncthreads();
    if (tid == 0) dists[q * 10 + c] = red[0] + red[1] + red[2] + red[3];
    __syncthreads();
  }
}

// ---------------------------------------------------------------------------
extern "C" void kernel_launch(void* const* d_in, const int* in_sizes, int n_in,
                              void* d_out, int out_size, void* d_ws, size_t ws_size,
                              hipStream_t stream) {
  const float* x = (const float*)d_in[0];
  const float* W1 = (const float*)d_in[1];
  const float* b1 = (const float*)d_in[2];
  const float* W2 = (const float*)d_in[3];
  const float* b2 = (const float*)d_in[4];
  float* out = (float*)d_out;

  float* f = (float*)d_ws;                       // 400*1024 f32
  float* a = f + ROWS_ * H_;                     // 400*1024 f32
  float* logits = a + ROWS_ * H_;                // 30000 f32
  unsigned short* Btc = (unsigned short*)(logits + 30000);  // 1024*1024 bf16
  unsigned short* Btd = Btc + H_ * H_;                      // 1024*1024 bf16

  feat_kernel<<<ROWS_ / 8, 256, 0, stream>>>(x, W1, b1, f);
  proj_kernel<<<13 + 38, 256, 0, stream>>>(f, W2, b2, a);
  trans_kernel<<<512, 256, 0, stream>>>(W2, Btc, Btd);
  hipMemsetAsync(logits, 0, 30000 * sizeof(float), stream);
  mca_mfma_kernel<<<10 * 19 * 4, 512, 0, stream>>>(f, a, Btc, Btd, logits);
  out_kernel<<<Q_, 256, 0, stream>>>(x, logits, out);
}

// Round 3
// 567.474 us; speedup vs baseline: 4.0258x; 1.1538x over previous
//
#include <hip/hip_runtime.h>
#include <hip/hip_bf16.h>
#include <math.h>

// ProtoInstanceMultiCrossAttention: C=10, S=10, NQ=30, H=1024
#define C_   10
#define S_   10
#define NQ_  30
#define H_   1024
#define Q_   300
#define ROWS_ 400

typedef __attribute__((ext_vector_type(8))) short s16x8;   // 8 bf16 (4 VGPRs)
typedef __attribute__((ext_vector_type(4))) float f32x4;   // MFMA acc

static __device__ __forceinline__ short f2b(float f) {
  __hip_bfloat16 h = __float2bfloat16(f);
  return __builtin_bit_cast(short, h);
}

static __device__ __forceinline__ float ftanh(float v) {
  v = fminf(fmaxf(v, -10.f), 10.f);
  float e = __expf(2.f * v);
  return (e - 1.f) / (e + 1.f);
}

// ---------------------------------------------------------------------------
// Kernel 1: f = x @ W1 + b1   (400 x 1024, K=1024)  -- fp32 VALU (small)
// ---------------------------------------------------------------------------
__global__ __launch_bounds__(256) void feat_kernel(
    const float* __restrict__ x, const float* __restrict__ W1,
    const float* __restrict__ b1, float* __restrict__ f) {
  __shared__ float xs[8][H_];
  const int r0 = blockIdx.x * 8;
  const int tid = threadIdx.x;
  for (int t = tid; t < 8 * H_; t += 256) {
    int r = t >> 10, h = t & 1023;
    xs[r][h] = x[(r0 + r) * H_ + h];
  }
  __syncthreads();
  float acc[8][4];
#pragma unroll
  for (int r = 0; r < 8; ++r)
#pragma unroll
    for (int j = 0; j < 4; ++j) acc[r][j] = 0.f;
#pragma unroll 2
  for (int h = 0; h < H_; ++h) {
    float w0 = W1[h * H_ + tid];
    float w1 = W1[h * H_ + tid + 256];
    float w2 = W1[h * H_ + tid + 512];
    float w3 = W1[h * H_ + tid + 768];
#pragma unroll
    for (int r = 0; r < 8; ++r) {
      float xv = xs[r][h];
      acc[r][0] = fmaf(xv, w0, acc[r][0]);
      acc[r][1] = fmaf(xv, w1, acc[r][1]);
      acc[r][2] = fmaf(xv, w2, acc[r][2]);
      acc[r][3] = fmaf(xv, w3, acc[r][3]);
    }
  }
#pragma unroll
  for (int r = 0; r < 8; ++r)
#pragma unroll
    for (int j = 0; j < 4; ++j) {
      int d = tid + 256 * j;
      f[(r0 + r) * H_ + d] = acc[r][j] + b1[d];
    }
}

// ---------------------------------------------------------------------------
// Kernel 2: a_s = sf @ Ws (100 rows), a_q = qf @ Wq + b2 (300 rows)
// ---------------------------------------------------------------------------
__global__ __launch_bounds__(256) void proj_kernel(
    const float* __restrict__ f, const float* __restrict__ W2,
    const float* __restrict__ b2, float* __restrict__ a) {
  const int b = blockIdx.x;
  const bool isSup = (b < 13);
  const int i0 = isSup ? b * 8 : (b - 13) * 8;
  const int n = isSup ? 100 : 300;
  const float* __restrict__ W = isSup ? W2 : (W2 + H_ * H_);

  __shared__ float fs[8][H_];
  const int tid = threadIdx.x;
  for (int t = tid; t < 8 * H_; t += 256) {
    int r = t >> 10, h = t & 1023;
    int i = i0 + r;
    if (i >= n) i = n - 1;
    int row = isSup ? ((i / 10) * 40 + (i % 10)) : ((i / 30) * 40 + 10 + (i % 30));
    fs[r][h] = f[row * H_ + h];
  }
  __syncthreads();
  float acc[8][4];
#pragma unroll
  for (int r = 0; r < 8; ++r)
#pragma unroll
    for (int j = 0; j < 4; ++j) acc[r][j] = 0.f;
#pragma unroll 2
  for (int h = 0; h < H_; ++h) {
    float w0 = W[h * H_ + tid];
    float w1 = W[h * H_ + tid + 256];
    float w2 = W[h * H_ + tid + 512];
    float w3 = W[h * H_ + tid + 768];
#pragma unroll
    for (int r = 0; r < 8; ++r) {
      float xv = fs[r][h];
      acc[r][0] = fmaf(xv, w0, acc[r][0]);
      acc[r][1] = fmaf(xv, w1, acc[r][1]);
      acc[r][2] = fmaf(xv, w2, acc[r][2]);
      acc[r][3] = fmaf(xv, w3, acc[r][3]);
    }
  }
#pragma unroll
  for (int r = 0; r < 8; ++r) {
    int i = i0 + r;
    if (i < n) {
      int o = isSup ? i : (100 + i);
#pragma unroll
      for (int j = 0; j < 4; ++j) {
        int d = tid + 256 * j;
        a[o * H_ + d] = acc[r][j] + (isSup ? 0.f : b2[d]);
      }
    }
  }
}

// ---------------------------------------------------------------------------
// Kernel 3: Bt[mat][n][k] = bf16(W[k][n]), mat 0=Wc 1=Wd. Block 512 zeroes
// logits (replaces hipMemsetAsync).  Grid 513 x 256.
// ---------------------------------------------------------------------------
__global__ __launch_bounds__(256) void trans_kernel(
    const float* __restrict__ W2, unsigned short* __restrict__ Bt,
    float* __restrict__ logits) {
  const int b = blockIdx.x;
  const int tid = threadIdx.x;
  if (b == 512) {
    float4* lz = (float4*)logits;
    for (int i = tid; i < 7500; i += 256) lz[i] = make_float4(0.f, 0.f, 0.f, 0.f);
    return;
  }
  const int mat = b >> 8, kt = (b >> 4) & 15, ntl = b & 15;
  const float* __restrict__ src =
      W2 + (size_t)(2 + mat) * H_ * H_ + (size_t)(kt * 64) * H_ + ntl * 64;
  __shared__ float tl[64][65];
  {
    int r = tid >> 2, c4 = (tid & 3) * 16;
    const float* srcp = src + (size_t)r * H_ + c4;
#pragma unroll
    for (int j = 0; j < 4; ++j) {
      float4 v = *(const float4*)(srcp + j * 4);
      tl[r][c4 + j * 4 + 0] = v.x;
      tl[r][c4 + j * 4 + 1] = v.y;
      tl[r][c4 + j * 4 + 2] = v.z;
      tl[r][c4 + j * 4 + 3] = v.w;
    }
  }
  __syncthreads();
  {
    int n = tid >> 2, k0t = (tid & 3) * 16;
    s16x8 o0, o1;
#pragma unroll
    for (int j = 0; j < 8; ++j) {
      o0[j] = f2b(tl[k0t + j][n]);
      o1[j] = f2b(tl[k0t + 8 + j][n]);
    }
    unsigned short* dstp = Bt + (size_t)mat * H_ * H_ +
                           (size_t)(ntl * 64 + n) * H_ + kt * 64 + k0t;
    *(s16x8*)dstp = o0;
    *(s16x8*)(dstp + 8) = o1;
  }
}

// ---------------------------------------------------------------------------
// Kernel 4 (dominant): bf16 MFMA fused mca, double-buffered, 1 barrier/step.
//   BM=160 (16q x 10s), BN=256, dual-k step 64 (32 src-k).
//   8 waves as 2(M) x 4(N): wave band = 80 rows x 64 cols -> per kk:
//   5 A-frag + 4 B-frag ds_read_b128, 20 MFMA.
//   A generated from f (global, L2-hot) in write-phase; B staged from Bt.
// Grid: c(10) x qt(19) x nt(4) = 760 blocks, 512 threads. LDS 104 KB.
// ---------------------------------------------------------------------------
__global__ __launch_bounds__(512, 2) void mca_mfma_kernel(
    const float* __restrict__ f, const float* __restrict__ a,
    const unsigned short* __restrict__ Bt, float* __restrict__ logits) {
  const int b = blockIdx.x;
  const int nt = b & 3;
  const int qt = (b >> 2) % 19;
  const int c = (b >> 2) / 19;
  const int q0 = qt * 16;
  const int n0 = nt * 256;

  __shared__ unsigned short Als[2][160 * 64];  // 2 x 20 KB
  __shared__ unsigned short Bls[2][256 * 64];  // 2 x 32 KB

  const int tid = threadIdx.x;
  const int w = tid >> 6, lane = tid & 63;

  // ---- A-gen task precompute: task0 = tid, task1 = tid + 512 (tid < 128)
  const int row0 = tid >> 2, qtr = tid & 3;
  const int qloc0 = row0 / 10, s0 = row0 - qloc0 * 10;
  int q0g = q0 + qloc0; if (q0g > 299) q0g = 299;
  const float* sfp0 = f + (size_t)(c * 40 + s0) * H_ + qtr * 8;
  const float* qfp0 = f + (size_t)((q0g / 30) * 40 + 10 + (q0g % 30)) * H_ + qtr * 8;
  const unsigned asw0 = (unsigned)((row0 & 7) << 4);
  const unsigned aw0 = (unsigned)(row0 * 128 + qtr * 16);
  const bool has2 = (tid < 128);
  const int row1 = row0 + 128;
  const int qloc1 = row1 / 10, s1 = row1 - qloc1 * 10;
  int q1g = q0 + qloc1; if (q1g > 299) q1g = 299;
  const float* sfp1 = f + (size_t)(c * 40 + s1) * H_ + qtr * 8;
  const float* qfp1 = f + (size_t)((q1g / 30) * 40 + 10 + (q1g % 30)) * H_ + qtr * 8;
  const unsigned asw1 = (unsigned)((row1 & 7) << 4);
  const unsigned aw1 = (unsigned)(row1 * 128 + qtr * 16);

  // ---- B staging precompute
  const int bn = tid >> 1, bm = tid & 1;
  const unsigned short* bp = Bt + (size_t)bm * H_ * H_ + (size_t)(n0 + bn) * H_;
  const unsigned bw = (unsigned)(bn * 128 + bm * 64);
  const unsigned bsw = (unsigned)((bn & 7) << 4);

  // ---- MFMA-phase constants
  const int frow = lane & 15;
  const unsigned fkb = (unsigned)((lane >> 4) * 16);
  const unsigned swf = (unsigned)((frow & 7) << 4);
  const int wr = w >> 2, wc = w & 3;
  unsigned ard[5], brd[4];
#pragma unroll
  for (int m = 0; m < 5; ++m) ard[m] = (unsigned)((wr * 80 + m * 16 + frow) * 128);
#pragma unroll
  for (int nf = 0; nf < 4; ++nf) brd[nf] = (unsigned)((wc * 64 + nf * 16 + frow) * 128);

  f32x4 acc[5][4];
#pragma unroll
  for (int m = 0; m < 5; ++m)
#pragma unroll
    for (int nf = 0; nf < 4; ++nf) acc[m][nf] = (f32x4)(0.f);

  float4 SA0, SB0, QA0, QB0, SA1, SB1, QA1, QB1;
  s16x8 B0, B1, B2, B3;

#define ISSUE(KG)                                                              \
  do {                                                                         \
    SA0 = *(const float4*)(sfp0 + (KG));                                       \
    SB0 = *(const float4*)(sfp0 + (KG) + 4);                                   \
    QA0 = *(const float4*)(qfp0 + (KG));                                       \
    QB0 = *(const float4*)(qfp0 + (KG) + 4);                                   \
    if (has2) {                                                                \
      SA1 = *(const float4*)(sfp1 + (KG));                                     \
      SB1 = *(const float4*)(sfp1 + (KG) + 4);                                 \
      QA1 = *(const float4*)(qfp1 + (KG));                                     \
      QB1 = *(const float4*)(qfp1 + (KG) + 4);                                 \
    }                                                                          \
    B0 = *(const s16x8*)(bp + (KG));                                           \
    B1 = *(const s16x8*)(bp + (KG) + 8);                                       \
    B2 = *(const s16x8*)(bp + (KG) + 16);                                      \
    B3 = *(const s16x8*)(bp + (KG) + 24);                                      \
  } while (0)

#define GEN1(SA, SB, QA, QB, AWR, ASW, AB)                                     \
  do {                                                                         \
    s16x8 d1, d2;                                                              \
    d1[0] = f2b(fabsf(SA.x - QA.x)); d2[0] = f2b(SA.x * QA.x);                 \
    d1[1] = f2b(fabsf(SA.y - QA.y)); d2[1] = f2b(SA.y * QA.y);                 \
    d1[2] = f2b(fabsf(SA.z - QA.z)); d2[2] = f2b(SA.z * QA.z);                 \
    d1[3] = f2b(fabsf(SA.w - QA.w)); d2[3] = f2b(SA.w * QA.w);                 \
    d1[4] = f2b(fabsf(SB.x - QB.x)); d2[4] = f2b(SB.x * QB.x);                 \
    d1[5] = f2b(fabsf(SB.y - QB.y)); d2[5] = f2b(SB.y * QB.y);                 \
    d1[6] = f2b(fabsf(SB.z - QB.z)); d2[6] = f2b(SB.z * QB.z);                 \
    d1[7] = f2b(fabsf(SB.w - QB.w)); d2[7] = f2b(SB.w * QB.w);                 \
    *(s16x8*)((AB) + ((AWR) ^ (ASW))) = d1;                                    \
    *(s16x8*)((AB) + (((AWR) + 64) ^ (ASW))) = d2;                             \
  } while (0)

#define WTILE(P)                                                               \
  do {                                                                         \
    char* AB = (char*)&Als[P][0];                                              \
    char* BB = (char*)&Bls[P][0];                                              \
    *(s16x8*)(BB + ((bw + 0) ^ bsw)) = B0;                                     \
    *(s16x8*)(BB + ((bw + 16) ^ bsw)) = B1;                                    \
    *(s16x8*)(BB + ((bw + 32) ^ bsw)) = B2;                                    \
    *(s16x8*)(BB + ((bw + 48) ^ bsw)) = B3;                                    \
    GEN1(SA0, SB0, QA0, QB0, aw0, asw0, AB);                                   \
    if (has2) GEN1(SA1, SB1, QA1, QB1, aw1, asw1, AB);                         \
  } while (0)

#define MFMA_PHASE(P)                                                          \
  do {                                                                         \
    const char* AB = (const char*)&Als[P][0];                                  \
    const char* BB = (const char*)&Bls[P][0];                                  \
    _Pragma("unroll") for (int kk = 0; kk < 2; ++kk) {                         \
      const unsigned kb = fkb + kk * 64;                                       \
      s16x8 bf0 = *(const s16x8*)(BB + ((brd[0] + kb) ^ swf));                 \
      s16x8 bf1 = *(const s16x8*)(BB + ((brd[1] + kb) ^ swf));                 \
      s16x8 bf2 = *(const s16x8*)(BB + ((brd[2] + kb) ^ swf));                 \
      s16x8 bf3 = *(const s16x8*)(BB + ((brd[3] + kb) ^ swf));                 \
      _Pragma("unroll") for (int m = 0; m < 5; ++m) {                          \
        s16x8 af = *(const s16x8*)(AB + ((ard[m] + kb) ^ swf));                \
        acc[m][0] = __builtin_amdgcn_mfma_f32_16x16x32_bf16(af, bf0, acc[m][0], 0, 0, 0); \
        acc[m][1] = __builtin_amdgcn_mfma_f32_16x16x32_bf16(af, bf1, acc[m][1], 0, 0, 0); \
        acc[m][2] = __builtin_amdgcn_mfma_f32_16x16x32_bf16(af, bf2, acc[m][2], 0, 0, 0); \
        acc[m][3] = __builtin_amdgcn_mfma_f32_16x16x32_bf16(af, bf3, acc[m][3], 0, 0, 0); \
      }                                                                        \
    }                                                                          \
  } while (0)

  // prologue: stage K-step 0 into buffer 0
  ISSUE(0);
  WTILE(0);
  __syncthreads();

  int p = 0;
  for (int ks = 0; ks < 32; ++ks) {
    const int kn = (ks < 31 ? ks + 1 : 31) * 32;
    ISSUE(kn);  // prefetch next step (dummy refetch on last)
    __builtin_amdgcn_s_setprio(1);
    MFMA_PHASE(p);
    __builtin_amdgcn_s_setprio(0);
    if (ks < 31) WTILE(p ^ 1);
    __syncthreads();
    p ^= 1;
  }

  // ---- epilogue: + a_s + a_q(+b2), tanh, sum over d, reduce, atomicAdd
  const int colb = n0 + wc * 64 + frow;
  const int rgrp = (lane >> 4) * 4;
#pragma unroll
  for (int m = 0; m < 5; ++m) {
#pragma unroll
    for (int r = 0; r < 4; ++r) {
      const int row = wr * 80 + m * 16 + rgrp + r;
      const int qloc = row / 10, s = row - qloc * 10;
      const int q = q0 + qloc;
      float t = 0.f;
#pragma unroll
      for (int nf = 0; nf < 4; ++nf) {
        const int col = colb + nf * 16;
        float v = acc[m][nf][r] + a[(size_t)(c * 10 + s) * H_ + col] +
                  a[(size_t)(100 + q) * H_ + col];
        t += ftanh(v);
      }
      t += __shfl_xor(t, 1);
      t += __shfl_xor(t, 2);
      t += __shfl_xor(t, 4);
      t += __shfl_xor(t, 8);
      if ((lane & 15) == 0 && q < 300)
        atomicAdd(&logits[(q * 10 + c) * 10 + s], t);
    }
  }
#undef ISSUE
#undef GEN1
#undef WTILE
#undef MFMA_PHASE
}

// ---------------------------------------------------------------------------
// Kernel 5: softmax over s, proto, dists
// ---------------------------------------------------------------------------
__global__ __launch_bounds__(256) void out_kernel(
    const float* __restrict__ x, const float* __restrict__ logits,
    float* __restrict__ dists) {
  const int q = blockIdx.x;
  const int tid = threadIdx.x;
  const int lane = tid & 63;
  const int wave = tid >> 6;
  __shared__ float qrow[H_];
  __shared__ float red[4];

  const int qr = (q / 30) * 40 + 10 + (q % 30);
  for (int i = tid; i < H_; i += 256) qrow[i] = x[qr * H_ + i];
  __syncthreads();

  for (int c = 0; c < C_; ++c) {
    float l[S_];
    float m = -1e30f;
#pragma unroll
    for (int s = 0; s < S_; ++s) {
      l[s] = logits[(q * 10 + c) * 10 + s];
      m = fmaxf(m, l[s]);
    }
    float sum = 0.f;
    float sc[S_];
#pragma unroll
    for (int s = 0; s < S_; ++s) {
      sc[s] = __expf(l[s] - m);
      sum += sc[s];
    }
    float inv = 1.f / sum;
#pragma unroll
    for (int s = 0; s < S_; ++s) sc[s] *= inv;

    float part = 0.f;
    for (int i = tid; i < H_; i += 256) {
      float p = 0.f;
#pragma unroll
      for (int s = 0; s < S_; ++s) p = fmaf(sc[s], x[(c * 40 + s) * H_ + i], p);
      float d = p - qrow[i];
      part = fmaf(d, d, part);
    }
    for (int off = 32; off; off >>= 1) part += __shfl_down(part, off);
    if (lane == 0) red[wave] = part;
    __syncthreads();
    if (tid == 0) dists[q * 10 + c] = red[0] + red[1] + red[2] + red[3];
    __syncthreads();
  }
}

// ---------------------------------------------------------------------------
extern "C" void kernel_launch(void* const* d_in, const int* in_sizes, int n_in,
                              void* d_out, int out_size, void* d_ws, size_t ws_size,
                              hipStream_t stream) {
  const float* x = (const float*)d_in[0];
  const float* W1 = (const float*)d_in[1];
  const float* b1 = (const float*)d_in[2];
  const float* W2 = (const float*)d_in[3];
  const float* b2 = (const float*)d_in[4];
  float* out = (float*)d_out;

  float* f = (float*)d_ws;                       // 400*1024 f32
  float* a = f + ROWS_ * H_;                     // 400*1024 f32
  float* logits = a + ROWS_ * H_;                // 30000 f32 (+pad to float4)
  unsigned short* Bt = (unsigned short*)(logits + 30208);  // 2 x 1024 x 1024 bf16

  feat_kernel<<<ROWS_ / 8, 256, 0, stream>>>(x, W1, b1, f);
  proj_kernel<<<13 + 38, 256, 0, stream>>>(f, W2, b2, a);
  trans_kernel<<<513, 256, 0, stream>>>(W2, Bt, logits);
  mca_mfma_kernel<<<10 * 19 * 4, 512, 0, stream>>>(f, a, Bt, logits);
  out_kernel<<<Q_, 256, 0, stream>>>(x, logits, out);
}

// Round 4
// 325.369 us; speedup vs baseline: 7.0214x; 1.7441x over previous
//
#include <hip/hip_runtime.h>
#include <hip/hip_bf16.h>
#include <math.h>

// ProtoInstanceMultiCrossAttention: C=10, S=10, NQ=30, H=1024
#define C_   10
#define S_   10
#define NQ_  30
#define H_   1024
#define Q_   300
#define ROWS_ 400

typedef __attribute__((ext_vector_type(8))) short s16x8;   // 8 bf16 (4 VGPRs)
typedef __attribute__((ext_vector_type(4))) float f32x4;   // MFMA acc

static __device__ __forceinline__ short f2b(float f) {
  __hip_bfloat16 h = __float2bfloat16(f);
  return __builtin_bit_cast(short, h);
}

static __device__ __forceinline__ float ftanh(float v) {
  v = fminf(fmaxf(v, -10.f), 10.f);
  float e = __expf(2.f * v);
  return (e - 1.f) / (e + 1.f);
}

// ---------------------------------------------------------------------------
// Kernel 1: f = x @ W1 + b1  (400 x 1024, K=1024), fp32 VALU.
// Grid 100 row-tiles x 4 col-tiles = 400 blocks, 256 thr. Thread = 4 outputs.
// ---------------------------------------------------------------------------
__global__ __launch_bounds__(256) void feat_kernel(
    const float* __restrict__ x, const float* __restrict__ W1,
    const float* __restrict__ b1, float* __restrict__ f) {
  __shared__ float xs[4][H_];  // 16 KB
  const int rt = blockIdx.x % 100;
  const int nt = blockIdx.x / 100;
  const int r0 = rt * 4;
  const int n0 = nt * 256;
  const int tid = threadIdx.x;

  for (int t = tid; t < 4 * H_ / 4; t += 256) {
    int r = t >> 8, h4 = (t & 255) * 4;
    *(float4*)&xs[r][h4] = *(const float4*)&x[(size_t)(r0 + r) * H_ + h4];
  }
  __syncthreads();

  float acc0 = 0.f, acc1 = 0.f, acc2 = 0.f, acc3 = 0.f;
  const float* __restrict__ wp = W1 + n0 + tid;
#pragma unroll 8
  for (int h = 0; h < H_; ++h) {
    float w = wp[(size_t)h * H_];
    acc0 = fmaf(xs[0][h], w, acc0);
    acc1 = fmaf(xs[1][h], w, acc1);
    acc2 = fmaf(xs[2][h], w, acc2);
    acc3 = fmaf(xs[3][h], w, acc3);
  }
  const int col = n0 + tid;
  const float bb = b1[col];
  f[(size_t)(r0 + 0) * H_ + col] = acc0 + bb;
  f[(size_t)(r0 + 1) * H_ + col] = acc1 + bb;
  f[(size_t)(r0 + 2) * H_ + col] = acc2 + bb;
  f[(size_t)(r0 + 3) * H_ + col] = acc3 + bb;
}

// ---------------------------------------------------------------------------
// Kernel 2: a_s = sf @ Ws (100 rows), a_q = qf @ Wq + b2 (300 rows).
// Grid 100 row-tiles (25 sup + 75 qry) x 4 col-tiles = 400 blocks.
// ---------------------------------------------------------------------------
__global__ __launch_bounds__(256) void proj_kernel(
    const float* __restrict__ f, const float* __restrict__ W2,
    const float* __restrict__ b2, float* __restrict__ a) {
  __shared__ float fs[4][H_];
  const int rt = blockIdx.x % 100;
  const int nt = blockIdx.x / 100;
  const bool isSup = (rt < 25);
  const int i0 = isSup ? rt * 4 : (rt - 25) * 4;
  const int n0 = nt * 256;
  const float* __restrict__ W = isSup ? W2 : (W2 + (size_t)H_ * H_);
  const int tid = threadIdx.x;

  for (int t = tid; t < 4 * H_ / 4; t += 256) {
    int r = t >> 8, h4 = (t & 255) * 4;
    int i = i0 + r;
    int row = isSup ? ((i / 10) * 40 + (i % 10)) : ((i / 30) * 40 + 10 + (i % 30));
    *(float4*)&fs[r][h4] = *(const float4*)&f[(size_t)row * H_ + h4];
  }
  __syncthreads();

  float acc0 = 0.f, acc1 = 0.f, acc2 = 0.f, acc3 = 0.f;
  const float* __restrict__ wp = W + n0 + tid;
#pragma unroll 8
  for (int h = 0; h < H_; ++h) {
    float w = wp[(size_t)h * H_];
    acc0 = fmaf(fs[0][h], w, acc0);
    acc1 = fmaf(fs[1][h], w, acc1);
    acc2 = fmaf(fs[2][h], w, acc2);
    acc3 = fmaf(fs[3][h], w, acc3);
  }
  const int col = n0 + tid;
  const float bb = isSup ? 0.f : b2[col];
  const int o0 = isSup ? i0 : (100 + i0);
  a[(size_t)(o0 + 0) * H_ + col] = acc0 + bb;
  a[(size_t)(o0 + 1) * H_ + col] = acc1 + bb;
  a[(size_t)(o0 + 2) * H_ + col] = acc2 + bb;
  a[(size_t)(o0 + 3) * H_ + col] = acc3 + bb;
}

// ---------------------------------------------------------------------------
// Kernel 3: Bt[mat][n][k] = bf16(W[k][n]), mat 0=Wc 1=Wd. Block 512 zeroes
// logits.  Grid 513 x 256.
// ---------------------------------------------------------------------------
__global__ __launch_bounds__(256) void trans_kernel(
    const float* __restrict__ W2, unsigned short* __restrict__ Bt,
    float* __restrict__ logits) {
  const int b = blockIdx.x;
  const int tid = threadIdx.x;
  if (b == 512) {
    float4* lz = (float4*)logits;
    for (int i = tid; i < 7500; i += 256) lz[i] = make_float4(0.f, 0.f, 0.f, 0.f);
    return;
  }
  const int mat = b >> 8, kt = (b >> 4) & 15, ntl = b & 15;
  const float* __restrict__ src =
      W2 + (size_t)(2 + mat) * H_ * H_ + (size_t)(kt * 64) * H_ + ntl * 64;
  __shared__ float tl[64][65];
  {
    int r = tid >> 2, c4 = (tid & 3) * 16;
    const float* srcp = src + (size_t)r * H_ + c4;
#pragma unroll
    for (int j = 0; j < 4; ++j) {
      float4 v = *(const float4*)(srcp + j * 4);
      tl[r][c4 + j * 4 + 0] = v.x;
      tl[r][c4 + j * 4 + 1] = v.y;
      tl[r][c4 + j * 4 + 2] = v.z;
      tl[r][c4 + j * 4 + 3] = v.w;
    }
  }
  __syncthreads();
  {
    int n = tid >> 2, k0t = (tid & 3) * 16;
    s16x8 o0, o1;
#pragma unroll
    for (int j = 0; j < 8; ++j) {
      o0[j] = f2b(tl[k0t + j][n]);
      o1[j] = f2b(tl[k0t + 8 + j][n]);
    }
    unsigned short* dstp = Bt + (size_t)mat * H_ * H_ +
                           (size_t)(ntl * 64 + n) * H_ + kt * 64 + k0t;
    *(s16x8*)dstp = o0;
    *(s16x8*)(dstp + 8) = o1;
  }
}

// ---------------------------------------------------------------------------
// Kernel 4 (dominant): bf16 MFMA fused mca, double-buffered, 1 barrier/step.
// (unchanged from round 2)
// ---------------------------------------------------------------------------
__global__ __launch_bounds__(512, 2) void mca_mfma_kernel(
    const float* __restrict__ f, const float* __restrict__ a,
    const unsigned short* __restrict__ Bt, float* __restrict__ logits) {
  const int b = blockIdx.x;
  const int nt = b & 3;
  const int qt = (b >> 2) % 19;
  const int c = (b >> 2) / 19;
  const int q0 = qt * 16;
  const int n0 = nt * 256;

  __shared__ unsigned short Als[2][160 * 64];  // 2 x 20 KB
  __shared__ unsigned short Bls[2][256 * 64];  // 2 x 32 KB

  const int tid = threadIdx.x;
  const int w = tid >> 6, lane = tid & 63;

  const int row0 = tid >> 2, qtr = tid & 3;
  const int qloc0 = row0 / 10, s0 = row0 - qloc0 * 10;
  int q0g = q0 + qloc0; if (q0g > 299) q0g = 299;
  const float* sfp0 = f + (size_t)(c * 40 + s0) * H_ + qtr * 8;
  const float* qfp0 = f + (size_t)((q0g / 30) * 40 + 10 + (q0g % 30)) * H_ + qtr * 8;
  const unsigned asw0 = (unsigned)((row0 & 7) << 4);
  const unsigned aw0 = (unsigned)(row0 * 128 + qtr * 16);
  const bool has2 = (tid < 128);
  const int row1 = row0 + 128;
  const int qloc1 = row1 / 10, s1 = row1 - qloc1 * 10;
  int q1g = q0 + qloc1; if (q1g > 299) q1g = 299;
  const float* sfp1 = f + (size_t)(c * 40 + s1) * H_ + qtr * 8;
  const float* qfp1 = f + (size_t)((q1g / 30) * 40 + 10 + (q1g % 30)) * H_ + qtr * 8;
  const unsigned asw1 = (unsigned)((row1 & 7) << 4);
  const unsigned aw1 = (unsigned)(row1 * 128 + qtr * 16);

  const int bn = tid >> 1, bm = tid & 1;
  const unsigned short* bp = Bt + (size_t)bm * H_ * H_ + (size_t)(n0 + bn) * H_;
  const unsigned bw = (unsigned)(bn * 128 + bm * 64);
  const unsigned bsw = (unsigned)((bn & 7) << 4);

  const int frow = lane & 15;
  const unsigned fkb = (unsigned)((lane >> 4) * 16);
  const unsigned swf = (unsigned)((frow & 7) << 4);
  const int wr = w >> 2, wc = w & 3;
  unsigned ard[5], brd[4];
#pragma unroll
  for (int m = 0; m < 5; ++m) ard[m] = (unsigned)((wr * 80 + m * 16 + frow) * 128);
#pragma unroll
  for (int nf = 0; nf < 4; ++nf) brd[nf] = (unsigned)((wc * 64 + nf * 16 + frow) * 128);

  f32x4 acc[5][4];
#pragma unroll
  for (int m = 0; m < 5; ++m)
#pragma unroll
    for (int nf = 0; nf < 4; ++nf) acc[m][nf] = (f32x4)(0.f);

  float4 SA0, SB0, QA0, QB0, SA1, SB1, QA1, QB1;
  s16x8 B0, B1, B2, B3;

#define ISSUE(KG)                                                              \
  do {                                                                         \
    SA0 = *(const float4*)(sfp0 + (KG));                                       \
    SB0 = *(const float4*)(sfp0 + (KG) + 4);                                   \
    QA0 = *(const float4*)(qfp0 + (KG));                                       \
    QB0 = *(const float4*)(qfp0 + (KG) + 4);                                   \
    if (has2) {                                                                \
      SA1 = *(const float4*)(sfp1 + (KG));                                     \
      SB1 = *(const float4*)(sfp1 + (KG) + 4);                                 \
      QA1 = *(const float4*)(qfp1 + (KG));                                     \
      QB1 = *(const float4*)(qfp1 + (KG) + 4);                                 \
    }                                                                          \
    B0 = *(const s16x8*)(bp + (KG));                                           \
    B1 = *(const s16x8*)(bp + (KG) + 8);                                       \
    B2 = *(const s16x8*)(bp + (KG) + 16);                                      \
    B3 = *(const s16x8*)(bp + (KG) + 24);                                      \
  } while (0)

#define GEN1(SA, SB, QA, QB, AWR, ASW, AB)                                     \
  do {                                                                         \
    s16x8 d1, d2;                                                              \
    d1[0] = f2b(fabsf(SA.x - QA.x)); d2[0] = f2b(SA.x * QA.x);                 \
    d1[1] = f2b(fabsf(SA.y - QA.y)); d2[1] = f2b(SA.y * QA.y);                 \
    d1[2] = f2b(fabsf(SA.z - QA.z)); d2[2] = f2b(SA.z * QA.z);                 \
    d1[3] = f2b(fabsf(SA.w - QA.w)); d2[3] = f2b(SA.w * QA.w);                 \
    d1[4] = f2b(fabsf(SB.x - QB.x)); d2[4] = f2b(SB.x * QB.x);                 \
    d1[5] = f2b(fabsf(SB.y - QB.y)); d2[5] = f2b(SB.y * QB.y);                 \
    d1[6] = f2b(fabsf(SB.z - QB.z)); d2[6] = f2b(SB.z * QB.z);                 \
    d1[7] = f2b(fabsf(SB.w - QB.w)); d2[7] = f2b(SB.w * QB.w);                 \
    *(s16x8*)((AB) + ((AWR) ^ (ASW))) = d1;                                    \
    *(s16x8*)((AB) + (((AWR) + 64) ^ (ASW))) = d2;                             \
  } while (0)

#define WTILE(P)                                                               \
  do {                                                                         \
    char* AB = (char*)&Als[P][0];                                              \
    char* BB = (char*)&Bls[P][0];                                              \
    *(s16x8*)(BB + ((bw + 0) ^ bsw)) = B0;                                     \
    *(s16x8*)(BB + ((bw + 16) ^ bsw)) = B1;                                    \
    *(s16x8*)(BB + ((bw + 32) ^ bsw)) = B2;                                    \
    *(s16x8*)(BB + ((bw + 48) ^ bsw)) = B3;                                    \
    GEN1(SA0, SB0, QA0, QB0, aw0, asw0, AB);                                   \
    if (has2) GEN1(SA1, SB1, QA1, QB1, aw1, asw1, AB);                         \
  } while (0)

#define MFMA_PHASE(P)                                                          \
  do {                                                                         \
    const char* AB = (const char*)&Als[P][0];                                  \
    const char* BB = (const char*)&Bls[P][0];                                  \
    _Pragma("unroll") for (int kk = 0; kk < 2; ++kk) {                         \
      const unsigned kb = fkb + kk * 64;                                       \
      s16x8 bf0 = *(const s16x8*)(BB + ((brd[0] + kb) ^ swf));                 \
      s16x8 bf1 = *(const s16x8*)(BB + ((brd[1] + kb) ^ swf));                 \
      s16x8 bf2 = *(const s16x8*)(BB + ((brd[2] + kb) ^ swf));                 \
      s16x8 bf3 = *(const s16x8*)(BB + ((brd[3] + kb) ^ swf));                 \
      _Pragma("unroll") for (int m = 0; m < 5; ++m) {                          \
        s16x8 af = *(const s16x8*)(AB + ((ard[m] + kb) ^ swf));                \
        acc[m][0] = __builtin_amdgcn_mfma_f32_16x16x32_bf16(af, bf0, acc[m][0], 0, 0, 0); \
        acc[m][1] = __builtin_amdgcn_mfma_f32_16x16x32_bf16(af, bf1, acc[m][1], 0, 0, 0); \
        acc[m][2] = __builtin_amdgcn_mfma_f32_16x16x32_bf16(af, bf2, acc[m][2], 0, 0, 0); \
        acc[m][3] = __builtin_amdgcn_mfma_f32_16x16x32_bf16(af, bf3, acc[m][3], 0, 0, 0); \
      }                                                                        \
    }                                                                          \
  } while (0)

  ISSUE(0);
  WTILE(0);
  __syncthreads();

  int p = 0;
  for (int ks = 0; ks < 32; ++ks) {
    const int kn = (ks < 31 ? ks + 1 : 31) * 32;
    ISSUE(kn);
    __builtin_amdgcn_s_setprio(1);
    MFMA_PHASE(p);
    __builtin_amdgcn_s_setprio(0);
    if (ks < 31) WTILE(p ^ 1);
    __syncthreads();
    p ^= 1;
  }

  const int colb = n0 + wc * 64 + frow;
  const int rgrp = (lane >> 4) * 4;
#pragma unroll
  for (int m = 0; m < 5; ++m) {
#pragma unroll
    for (int r = 0; r < 4; ++r) {
      const int row = wr * 80 + m * 16 + rgrp + r;
      const int qloc = row / 10, s = row - qloc * 10;
      const int q = q0 + qloc;
      float t = 0.f;
#pragma unroll
      for (int nf = 0; nf < 4; ++nf) {
        const int col = colb + nf * 16;
        float v = acc[m][nf][r] + a[(size_t)(c * 10 + s) * H_ + col] +
                  a[(size_t)(100 + q) * H_ + col];
        t += ftanh(v);
      }
      t += __shfl_xor(t, 1);
      t += __shfl_xor(t, 2);
      t += __shfl_xor(t, 4);
      t += __shfl_xor(t, 8);
      if ((lane & 15) == 0 && q < 300)
        atomicAdd(&logits[(q * 10 + c) * 10 + s], t);
    }
  }
#undef ISSUE
#undef GEN1
#undef WTILE
#undef MFMA_PHASE
}

// ---------------------------------------------------------------------------
// Kernel 5: softmax over s, proto, dists. One block per (q,c): 3000 blocks.
// ---------------------------------------------------------------------------
__global__ __launch_bounds__(256) void out_kernel(
    const float* __restrict__ x, const float* __restrict__ logits,
    float* __restrict__ dists) {
  const int q = blockIdx.x / 10;
  const int c = blockIdx.x % 10;
  const int tid = threadIdx.x;
  const int lane = tid & 63;
  const int wave = tid >> 6;
  __shared__ float red[4];

  // softmax over s (10 elems, all threads redundantly)
  float l[S_];
  float m = -1e30f;
#pragma unroll
  for (int s = 0; s < S_; ++s) {
    l[s] = logits[(q * 10 + c) * 10 + s];
    m = fmaxf(m, l[s]);
  }
  float sum = 0.f;
  float sc[S_];
#pragma unroll
  for (int s = 0; s < S_; ++s) {
    sc[s] = __expf(l[s] - m);
    sum += sc[s];
  }
  float inv = 1.f / sum;
#pragma unroll
  for (int s = 0; s < S_; ++s) sc[s] *= inv;

  const int qr = (q / 30) * 40 + 10 + (q % 30);
  float part = 0.f;
#pragma unroll
  for (int ii = 0; ii < 4; ++ii) {
    int i = tid + ii * 256;
    float p = 0.f;
#pragma unroll
    for (int s = 0; s < S_; ++s)
      p = fmaf(sc[s], x[(size_t)(c * 40 + s) * H_ + i], p);
    float d = p - x[(size_t)qr * H_ + i];
    part = fmaf(d, d, part);
  }
  for (int off = 32; off; off >>= 1) part += __shfl_down(part, off);
  if (lane == 0) red[wave] = part;
  __syncthreads();
  if (tid == 0) dists[q * 10 + c] = red[0] + red[1] + red[2] + red[3];
}

// ---------------------------------------------------------------------------
extern "C" void kernel_launch(void* const* d_in, const int* in_sizes, int n_in,
                              void* d_out, int out_size, void* d_ws, size_t ws_size,
                              hipStream_t stream) {
  const float* x = (const float*)d_in[0];
  const float* W1 = (const float*)d_in[1];
  const float* b1 = (const float*)d_in[2];
  const float* W2 = (const float*)d_in[3];
  const float* b2 = (const float*)d_in[4];
  float* out = (float*)d_out;

  float* f = (float*)d_ws;                       // 400*1024 f32
  float* a = f + ROWS_ * H_;                     // 400*1024 f32
  float* logits = a + ROWS_ * H_;                // 30000 f32 (+pad)
  unsigned short* Bt = (unsigned short*)(logits + 30208);  // 2 x 1024 x 1024 bf16

  feat_kernel<<<400, 256, 0, stream>>>(x, W1, b1, f);
  proj_kernel<<<400, 256, 0, stream>>>(f, W2, b2, a);
  trans_kernel<<<513, 256, 0, stream>>>(W2, Bt, logits);
  mca_mfma_kernel<<<10 * 19 * 4, 512, 0, stream>>>(f, a, Bt, logits);
  out_kernel<<<3000, 256, 0, stream>>>(x, logits, out);
}

// Round 5
// 322.026 us; speedup vs baseline: 7.0943x; 1.0104x over previous
//
#include <hip/hip_runtime.h>
#include <hip/hip_bf16.h>
#include <math.h>

// ProtoInstanceMultiCrossAttention: C=10, S=10, NQ=30, H=1024
#define C_   10
#define S_   10
#define NQ_  30
#define H_   1024
#define Q_   300
#define ROWS_ 400

typedef __attribute__((ext_vector_type(8))) short s16x8;   // 8 bf16 (4 VGPRs)
typedef __attribute__((ext_vector_type(4))) float f32x4;   // MFMA acc

static __device__ __forceinline__ short f2b(float f) {
  __hip_bfloat16 h = __float2bfloat16(f);
  return __builtin_bit_cast(short, h);
}

static __device__ __forceinline__ float ftanh(float v) {
  v = fminf(fmaxf(v, -10.f), 10.f);
  float e = __expf(2.f * v);
  return (e - 1.f) / (e + 1.f);
}

// ---------------------------------------------------------------------------
// Kernel 1: f = x @ W1 + b1  (400 x 1024, K=1024), fp32 VALU.
// ---------------------------------------------------------------------------
__global__ __launch_bounds__(256) void feat_kernel(
    const float* __restrict__ x, const float* __restrict__ W1,
    const float* __restrict__ b1, float* __restrict__ f) {
  __shared__ float xs[4][H_];  // 16 KB
  const int rt = blockIdx.x % 100;
  const int nt = blockIdx.x / 100;
  const int r0 = rt * 4;
  const int n0 = nt * 256;
  const int tid = threadIdx.x;

  for (int t = tid; t < 4 * H_ / 4; t += 256) {
    int r = t >> 8, h4 = (t & 255) * 4;
    *(float4*)&xs[r][h4] = *(const float4*)&x[(size_t)(r0 + r) * H_ + h4];
  }
  __syncthreads();

  float acc0 = 0.f, acc1 = 0.f, acc2 = 0.f, acc3 = 0.f;
  const float* __restrict__ wp = W1 + n0 + tid;
#pragma unroll 8
  for (int h = 0; h < H_; ++h) {
    float w = wp[(size_t)h * H_];
    acc0 = fmaf(xs[0][h], w, acc0);
    acc1 = fmaf(xs[1][h], w, acc1);
    acc2 = fmaf(xs[2][h], w, acc2);
    acc3 = fmaf(xs[3][h], w, acc3);
  }
  const int col = n0 + tid;
  const float bb = b1[col];
  f[(size_t)(r0 + 0) * H_ + col] = acc0 + bb;
  f[(size_t)(r0 + 1) * H_ + col] = acc1 + bb;
  f[(size_t)(r0 + 2) * H_ + col] = acc2 + bb;
  f[(size_t)(r0 + 3) * H_ + col] = acc3 + bb;
}

// ---------------------------------------------------------------------------
// Kernel 2: a_s = sf @ Ws (100 rows), a_q = qf @ Wq + b2 (300 rows).
// ---------------------------------------------------------------------------
__global__ __launch_bounds__(256) void proj_kernel(
    const float* __restrict__ f, const float* __restrict__ W2,
    const float* __restrict__ b2, float* __restrict__ a) {
  __shared__ float fs[4][H_];
  const int rt = blockIdx.x % 100;
  const int nt = blockIdx.x / 100;
  const bool isSup = (rt < 25);
  const int i0 = isSup ? rt * 4 : (rt - 25) * 4;
  const int n0 = nt * 256;
  const float* __restrict__ W = isSup ? W2 : (W2 + (size_t)H_ * H_);
  const int tid = threadIdx.x;

  for (int t = tid; t < 4 * H_ / 4; t += 256) {
    int r = t >> 8, h4 = (t & 255) * 4;
    int i = i0 + r;
    int row = isSup ? ((i / 10) * 40 + (i % 10)) : ((i / 30) * 40 + 10 + (i % 30));
    *(float4*)&fs[r][h4] = *(const float4*)&f[(size_t)row * H_ + h4];
  }
  __syncthreads();

  float acc0 = 0.f, acc1 = 0.f, acc2 = 0.f, acc3 = 0.f;
  const float* __restrict__ wp = W + n0 + tid;
#pragma unroll 8
  for (int h = 0; h < H_; ++h) {
    float w = wp[(size_t)h * H_];
    acc0 = fmaf(fs[0][h], w, acc0);
    acc1 = fmaf(fs[1][h], w, acc1);
    acc2 = fmaf(fs[2][h], w, acc2);
    acc3 = fmaf(fs[3][h], w, acc3);
  }
  const int col = n0 + tid;
  const float bb = isSup ? 0.f : b2[col];
  const int o0 = isSup ? i0 : (100 + i0);
  a[(size_t)(o0 + 0) * H_ + col] = acc0 + bb;
  a[(size_t)(o0 + 1) * H_ + col] = acc1 + bb;
  a[(size_t)(o0 + 2) * H_ + col] = acc2 + bb;
  a[(size_t)(o0 + 3) * H_ + col] = acc3 + bb;
}

// ---------------------------------------------------------------------------
// Kernel 3: Bt[mat][n][k] = bf16(W[k][n]), mat 0=Wc 1=Wd. Block 512 zeroes
// logits.  Grid 513 x 256.
// ---------------------------------------------------------------------------
__global__ __launch_bounds__(256) void trans_kernel(
    const float* __restrict__ W2, unsigned short* __restrict__ Bt,
    float* __restrict__ logits) {
  const int b = blockIdx.x;
  const int tid = threadIdx.x;
  if (b == 512) {
    float4* lz = (float4*)logits;
    for (int i = tid; i < 7500; i += 256) lz[i] = make_float4(0.f, 0.f, 0.f, 0.f);
    return;
  }
  const int mat = b >> 8, kt = (b >> 4) & 15, ntl = b & 15;
  const float* __restrict__ src =
      W2 + (size_t)(2 + mat) * H_ * H_ + (size_t)(kt * 64) * H_ + ntl * 64;
  __shared__ float tl[64][65];
  {
    int r = tid >> 2, c4 = (tid & 3) * 16;
    const float* srcp = src + (size_t)r * H_ + c4;
#pragma unroll
    for (int j = 0; j < 4; ++j) {
      float4 v = *(const float4*)(srcp + j * 4);
      tl[r][c4 + j * 4 + 0] = v.x;
      tl[r][c4 + j * 4 + 1] = v.y;
      tl[r][c4 + j * 4 + 2] = v.z;
      tl[r][c4 + j * 4 + 3] = v.w;
    }
  }
  __syncthreads();
  {
    int n = tid >> 2, k0t = (tid & 3) * 16;
    s16x8 o0, o1;
#pragma unroll
    for (int j = 0; j < 8; ++j) {
      o0[j] = f2b(tl[k0t + j][n]);
      o1[j] = f2b(tl[k0t + 8 + j][n]);
    }
    unsigned short* dstp = Bt + (size_t)mat * H_ * H_ +
                           (size_t)(ntl * 64 + n) * H_ + kt * 64 + k0t;
    *(s16x8*)dstp = o0;
    *(s16x8*)(dstp + 8) = o1;
  }
}

// ---------------------------------------------------------------------------
// Kernel 4 (dominant): bf16 MFMA fused mca, double-buffered, 1 barrier/step.
//   BM=160 (16q x 10s), BN=128, dual-k step 64 (32 src-k). LDS 72 KB ->
//   2 blocks/CU. 8 waves = 2(M) x 4(N): wave = 80 rows x 32 cols.
// Grid: c(10) x qt(19) x nt(8) = 1520 blocks, 512 threads.
// ---------------------------------------------------------------------------
__global__ __launch_bounds__(512, 4) void mca_mfma_kernel(
    const float* __restrict__ f, const float* __restrict__ a,
    const unsigned short* __restrict__ Bt, float* __restrict__ logits) {
  const int b = blockIdx.x;
  const int nt = b & 7;
  const int qt = (b >> 3) % 19;
  const int c = (b >> 3) / 19;
  const int q0 = qt * 16;
  const int n0 = nt * 128;

  __shared__ unsigned short Als[2][160 * 64];  // 2 x 20 KB
  __shared__ unsigned short Bls[2][128 * 64];  // 2 x 16 KB

  const int tid = threadIdx.x;
  const int w = tid >> 6, lane = tid & 63;

  // ---- A-gen task precompute: task0 = tid, task1 = tid + 512 (tid < 128)
  const int row0 = tid >> 2, qtr = tid & 3;
  const int qloc0 = row0 / 10, s0 = row0 - qloc0 * 10;
  int q0g = q0 + qloc0; if (q0g > 299) q0g = 299;
  const float* sfp0 = f + (size_t)(c * 40 + s0) * H_ + qtr * 8;
  const float* qfp0 = f + (size_t)((q0g / 30) * 40 + 10 + (q0g % 30)) * H_ + qtr * 8;
  const unsigned asw0 = (unsigned)((row0 & 7) << 4);
  const unsigned aw0 = (unsigned)(row0 * 128 + qtr * 16);
  const bool has2 = (tid < 128);
  const int row1 = row0 + 128;
  const int qloc1 = row1 / 10, s1 = row1 - qloc1 * 10;
  int q1g = q0 + qloc1; if (q1g > 299) q1g = 299;
  const float* sfp1 = f + (size_t)(c * 40 + s1) * H_ + qtr * 8;
  const float* qfp1 = f + (size_t)((q1g / 30) * 40 + 10 + (q1g % 30)) * H_ + qtr * 8;
  const unsigned asw1 = (unsigned)((row1 & 7) << 4);
  const unsigned aw1 = (unsigned)(row1 * 128 + qtr * 16);

  // ---- B staging: 128 rows x 4 thr/row; bq picks (mat, k-half)
  const int bn = tid >> 2, bq = tid & 3;
  const unsigned short* bp = Bt + (size_t)(bq >> 1) * H_ * H_ +
                             (size_t)(n0 + bn) * H_ + (bq & 1) * 16;
  const unsigned bwr = (unsigned)(bn * 128 + bq * 32);
  const unsigned bsw = (unsigned)((bn & 7) << 4);

  // ---- MFMA-phase constants
  const int frow = lane & 15;
  const unsigned fkb = (unsigned)((lane >> 4) * 16);
  const unsigned swf = (unsigned)((frow & 7) << 4);
  const int wr = w >> 2, wc = w & 3;
  unsigned ard[5], brd[2];
#pragma unroll
  for (int m = 0; m < 5; ++m) ard[m] = (unsigned)((wr * 80 + m * 16 + frow) * 128);
#pragma unroll
  for (int nf = 0; nf < 2; ++nf) brd[nf] = (unsigned)((wc * 32 + nf * 16 + frow) * 128);

  f32x4 acc[5][2];
#pragma unroll
  for (int m = 0; m < 5; ++m)
#pragma unroll
    for (int nf = 0; nf < 2; ++nf) acc[m][nf] = (f32x4)(0.f);

  float4 SA0, SB0, QA0, QB0, SA1, SB1, QA1, QB1;
  s16x8 B0, B1;

#define ISSUE(KG)                                                              \
  do {                                                                         \
    SA0 = *(const float4*)(sfp0 + (KG));                                       \
    SB0 = *(const float4*)(sfp0 + (KG) + 4);                                   \
    QA0 = *(const float4*)(qfp0 + (KG));                                       \
    QB0 = *(const float4*)(qfp0 + (KG) + 4);                                   \
    if (has2) {                                                                \
      SA1 = *(const float4*)(sfp1 + (KG));                                     \
      SB1 = *(const float4*)(sfp1 + (KG) + 4);                                 \
      QA1 = *(const float4*)(qfp1 + (KG));                                     \
      QB1 = *(const float4*)(qfp1 + (KG) + 4);                                 \
    }                                                                          \
    B0 = *(const s16x8*)(bp + (KG));                                           \
    B1 = *(const s16x8*)(bp + (KG) + 8);                                       \
  } while (0)

#define GEN1(SA, SB, QA, QB, AWR, ASW, AB)                                     \
  do {                                                                         \
    s16x8 d1, d2;                                                              \
    d1[0] = f2b(fabsf(SA.x - QA.x)); d2[0] = f2b(SA.x * QA.x);                 \
    d1[1] = f2b(fabsf(SA.y - QA.y)); d2[1] = f2b(SA.y * QA.y);                 \
    d1[2] = f2b(fabsf(SA.z - QA.z)); d2[2] = f2b(SA.z * QA.z);                 \
    d1[3] = f2b(fabsf(SA.w - QA.w)); d2[3] = f2b(SA.w * QA.w);                 \
    d1[4] = f2b(fabsf(SB.x - QB.x)); d2[4] = f2b(SB.x * QB.x);                 \
    d1[5] = f2b(fabsf(SB.y - QB.y)); d2[5] = f2b(SB.y * QB.y);                 \
    d1[6] = f2b(fabsf(SB.z - QB.z)); d2[6] = f2b(SB.z * QB.z);                 \
    d1[7] = f2b(fabsf(SB.w - QB.w)); d2[7] = f2b(SB.w * QB.w);                 \
    *(s16x8*)((AB) + ((AWR) ^ (ASW))) = d1;                                    \
    *(s16x8*)((AB) + (((AWR) + 64) ^ (ASW))) = d2;                             \
  } while (0)

#define WTILE(P)                                                               \
  do {                                                                         \
    char* AB = (char*)&Als[P][0];                                              \
    char* BB = (char*)&Bls[P][0];                                              \
    *(s16x8*)(BB + ((bwr + 0) ^ bsw)) = B0;                                    \
    *(s16x8*)(BB + ((bwr + 16) ^ bsw)) = B1;                                   \
    GEN1(SA0, SB0, QA0, QB0, aw0, asw0, AB);                                   \
    if (has2) GEN1(SA1, SB1, QA1, QB1, aw1, asw1, AB);                         \
  } while (0)

#define MFMA_PHASE(P)                                                          \
  do {                                                                         \
    const char* AB = (const char*)&Als[P][0];                                  \
    const char* BB = (const char*)&Bls[P][0];                                  \
    _Pragma("unroll") for (int kk = 0; kk < 2; ++kk) {                         \
      const unsigned kb = fkb + kk * 64;                                       \
      s16x8 bf0 = *(const s16x8*)(BB + ((brd[0] + kb) ^ swf));                 \
      s16x8 bf1 = *(const s16x8*)(BB + ((brd[1] + kb) ^ swf));                 \
      _Pragma("unroll") for (int m = 0; m < 5; ++m) {                          \
        s16x8 af = *(const s16x8*)(AB + ((ard[m] + kb) ^ swf));                \
        acc[m][0] = __builtin_amdgcn_mfma_f32_16x16x32_bf16(af, bf0, acc[m][0], 0, 0, 0); \
        acc[m][1] = __builtin_amdgcn_mfma_f32_16x16x32_bf16(af, bf1, acc[m][1], 0, 0, 0); \
      }                                                                        \
    }                                                                          \
  } while (0)

  ISSUE(0);
  WTILE(0);
  __syncthreads();

  int p = 0;
  for (int ks = 0; ks < 32; ++ks) {
    const int kn = (ks < 31 ? ks + 1 : 31) * 32;
    ISSUE(kn);
    __builtin_amdgcn_s_setprio(1);
    MFMA_PHASE(p);
    __builtin_amdgcn_s_setprio(0);
    if (ks < 31) WTILE(p ^ 1);
    __syncthreads();
    p ^= 1;
  }

  // ---- epilogue: + a_s + a_q(+b2), tanh, sum over d, reduce, atomicAdd
  const int colb = n0 + wc * 32 + frow;
  const int rgrp = (lane >> 4) * 4;
#pragma unroll
  for (int m = 0; m < 5; ++m) {
#pragma unroll
    for (int r = 0; r < 4; ++r) {
      const int row = wr * 80 + m * 16 + rgrp + r;
      const int qloc = row / 10, s = row - qloc * 10;
      const int q = q0 + qloc;
      float t = 0.f;
#pragma unroll
      for (int nf = 0; nf < 2; ++nf) {
        const int col = colb + nf * 16;
        float v = acc[m][nf][r] + a[(size_t)(c * 10 + s) * H_ + col] +
                  a[(size_t)(100 + q) * H_ + col];
        t += ftanh(v);
      }
      t += __shfl_xor(t, 1);
      t += __shfl_xor(t, 2);
      t += __shfl_xor(t, 4);
      t += __shfl_xor(t, 8);
      if ((lane & 15) == 0 && q < 300)
        atomicAdd(&logits[(q * 10 + c) * 10 + s], t);
    }
  }
#undef ISSUE
#undef GEN1
#undef WTILE
#undef MFMA_PHASE
}

// ---------------------------------------------------------------------------
// Kernel 5: softmax over s, proto, dists. One block per (q,c): 3000 blocks.
// ---------------------------------------------------------------------------
__global__ __launch_bounds__(256) void out_kernel(
    const float* __restrict__ x, const float* __restrict__ logits,
    float* __restrict__ dists) {
  const int q = blockIdx.x / 10;
  const int c = blockIdx.x % 10;
  const int tid = threadIdx.x;
  const int lane = tid & 63;
  const int wave = tid >> 6;
  __shared__ float red[4];

  float l[S_];
  float m = -1e30f;
#pragma unroll
  for (int s = 0; s < S_; ++s) {
    l[s] = logits[(q * 10 + c) * 10 + s];
    m = fmaxf(m, l[s]);
  }
  float sum = 0.f;
  float sc[S_];
#pragma unroll
  for (int s = 0; s < S_; ++s) {
    sc[s] = __expf(l[s] - m);
    sum += sc[s];
  }
  float inv = 1.f / sum;
#pragma unroll
  for (int s = 0; s < S_; ++s) sc[s] *= inv;

  const int qr = (q / 30) * 40 + 10 + (q % 30);
  float part = 0.f;
#pragma unroll
  for (int ii = 0; ii < 4; ++ii) {
    int i = tid + ii * 256;
    float p = 0.f;
#pragma unroll
    for (int s = 0; s < S_; ++s)
      p = fmaf(sc[s], x[(size_t)(c * 40 + s) * H_ + i], p);
    float d = p - x[(size_t)qr * H_ + i];
    part = fmaf(d, d, part);
  }
  for (int off = 32; off; off >>= 1) part += __shfl_down(part, off);
  if (lane == 0) red[wave] = part;
  __syncthreads();
  if (tid == 0) dists[q * 10 + c] = red[0] + red[1] + red[2] + red[3];
}

// ---------------------------------------------------------------------------
extern "C" void kernel_launch(void* const* d_in, const int* in_sizes, int n_in,
                              void* d_out, int out_size, void* d_ws, size_t ws_size,
                              hipStream_t stream) {
  const float* x = (const float*)d_in[0];
  const float* W1 = (const float*)d_in[1];
  const float* b1 = (const float*)d_in[2];
  const float* W2 = (const float*)d_in[3];
  const float* b2 = (const float*)d_in[4];
  float* out = (float*)d_out;

  float* f = (float*)d_ws;                       // 400*1024 f32
  float* a = f + ROWS_ * H_;                     // 400*1024 f32
  float* logits = a + ROWS_ * H_;                // 30000 f32 (+pad)
  unsigned short* Bt = (unsigned short*)(logits + 30208);  // 2 x 1024 x 1024 bf16

  feat_kernel<<<400, 256, 0, stream>>>(x, W1, b1, f);
  proj_kernel<<<400, 256, 0, stream>>>(f, W2, b2, a);
  trans_kernel<<<513, 256, 0, stream>>>(W2, Bt, logits);
  mca_mfma_kernel<<<10 * 19 * 8, 512, 0, stream>>>(f, a, Bt, logits);
  out_kernel<<<3000, 256, 0, stream>>>(x, logits, out);
}